// Round 10
// baseline (119.267 us; speedup 1.0000x reference)
//
#include <hip/hip_runtime.h>

typedef _Float16 f16;
typedef _Float16 f16x4 __attribute__((ext_vector_type(4)));
typedef _Float16 f16x8 __attribute__((ext_vector_type(8)));
typedef float f32x4 __attribute__((ext_vector_type(4)));

#define MFMA16(a, b, c) __builtin_amdgcn_mfma_f32_16x16x32_f16(a, b, c, 0, 0, 0)

constexpr int T = 2048;
constexpr int E = 1024;
constexpr int H = 16;
constexpr int D = 64;
constexpr int WIN = 256;
#define NEGF (-1e30f)
#define L2E 1.4426950408889634f

// async global->LDS, 16B per lane; LDS base must be wave-uniform (HW: base + lane*16)
__device__ __forceinline__ void gload16(const f16* g, f16* l) {
  __builtin_amdgcn_global_load_lds(
      (__attribute__((address_space(1))) void*)(void*)g,
      (__attribute__((address_space(3))) void*)(void*)l, 16, 0, 0);
}

// ---------------- cast x (f32 -> f16) ----------------
__global__ __launch_bounds__(256) void cast_x_kernel(const float* __restrict__ x,
                                                     f16* __restrict__ xb) {
  int idx = (blockIdx.x * 256 + threadIdx.x) * 4;
  float4 v = *(const float4*)(x + idx);
  f16x4 o = {(f16)v.x, (f16)v.y, (f16)v.z, (f16)v.w};
  *(f16x4*)(xb + idx) = o;
}

// ---------------- transpose+cast weights: w[K,N] f32 -> wT[N,K] f16 ----------------
__global__ __launch_bounds__(256) void transpose_w_kernel(
    const float* __restrict__ w0, const float* __restrict__ w1,
    const float* __restrict__ w2, const float* __restrict__ w3,
    f16* __restrict__ o0, f16* __restrict__ o1, f16* __restrict__ o2,
    f16* __restrict__ o3) {
  int z = blockIdx.z;
  const float* w = z == 0 ? w0 : z == 1 ? w1 : z == 2 ? w2 : w3;
  f16* o = z == 0 ? o0 : z == 1 ? o1 : z == 2 ? o2 : o3;
  __shared__ float tile[64][65];
  int k0 = blockIdx.x * 64, n0 = blockIdx.y * 64;
  int r = threadIdx.x >> 2, cb = (threadIdx.x & 3) * 16;
  const float* src = w + (size_t)(k0 + r) * E + n0 + cb;
#pragma unroll
  for (int j = 0; j < 16; j += 4) {
    float4 v = *(const float4*)(src + j);
    tile[r][cb + j] = v.x;
    tile[r][cb + j + 1] = v.y;
    tile[r][cb + j + 2] = v.z;
    tile[r][cb + j + 3] = v.w;
  }
  __syncthreads();
  f16 tmp[16];
#pragma unroll
  for (int j = 0; j < 16; ++j) tmp[j] = (f16)tile[cb + j][r];
  f16* dst = o + (size_t)(n0 + r) * E + k0 + cb;
  *(f16x8*)dst = *(f16x8*)&tmp[0];
  *(f16x8*)(dst + 8) = *(f16x8*)&tmp[8];
}

// ---------------- GEMM: C[M,N] = A[M,K] * Bt[N,K]^T + bias ----------------
// 128x128 tile, BK=32, 4 waves (2x2), mfma 16x16x32 f16 (one MFMA slab per
// K-step). 3-buffer pipeline with COUNTED vmcnt: stage(t+2) issued each step,
// s_waitcnt vmcnt(4) waits only tile t+1 -> tile t+2's loads stay in flight
// across the barrier (never drain to 0 in steady state). LDS 48KB, ~3 blk/CU.
// Swizzle (32-col tiles): col ^ ((row&3)<<3), same involution both sides.
// QKV=1: z=0/1 -> fused RMSNorm epilogue (q folds 0.125), z=2 -> V-transpose.
// QKV=0: plain f32 + bias epilogue.
template <int QKV>
__global__ __launch_bounds__(256) void gemm_bt_kernel(
    const f16* __restrict__ A, const f16* __restrict__ B0,
    const f16* __restrict__ B1, const f16* __restrict__ B2,
    const float* __restrict__ c0, const float* __restrict__ c1,
    const float* __restrict__ c2, const float* __restrict__ qnw,
    const float* __restrict__ knw, f16* __restrict__ oq, f16* __restrict__ ok,
    f16* __restrict__ Vt, float* __restrict__ of32, int M, int N, int K) {
  int z = blockIdx.z;
  const f16* Bt = z == 0 ? B0 : z == 1 ? B1 : B2;
  const float* bias = z == 0 ? c0 : z == 1 ? c1 : c2;

  __shared__ f16 lA[3][4096];  // 128 rows x 32 cols per buffer
  __shared__ f16 lB[3][4096];

  int m0 = blockIdx.x * 128, n0 = blockIdx.y * 128;
  int tid = threadIdx.x;
  int wid = tid >> 6, lane = tid & 63;
  int wm = wid >> 1, wn = wid & 1;
  int lr = lane & 15, lg = lane >> 4;

  f32x4 zero = {0.f, 0.f, 0.f, 0.f};
  f32x4 acc[4][4];
  for (int a = 0; a < 4; ++a)
    for (int b = 0; b < 4; ++b) acc[a][b] = zero;

  // staging geometry: per call, wave covers 16 rows x 32 cols (512 f16)
  int srow = lane >> 2;          // 0..15 row within 16-row stripe
  int scol = (lane & 3) << 3;    // 0/8/16/24 (f16 units)

  auto stage = [&](int buf, int k0) {
#pragma unroll
    for (int p = 0; p < 2; ++p) {
      int cc = (wid << 1) + p;   // 8 calls cover 128x32 tile
      int row = (cc << 4) + srow;
      int gc = scol ^ ((row & 3) << 3);  // inverse-swizzled source col
      gload16(A + (size_t)(m0 + row) * K + k0 + gc, &lA[buf][cc << 9]);
      gload16(Bt + (size_t)(n0 + row) * K + k0 + gc, &lB[buf][cc << 9]);
    }
  };

  int nit = K >> 5;              // 32 steps
  stage(0, 0);
  stage(1, 32);
  asm volatile("s_waitcnt vmcnt(4)" ::: "memory");  // buf0 landed
  __builtin_amdgcn_s_barrier();
  __builtin_amdgcn_sched_barrier(0);

  int cur = 0;
  int kc = lg << 3;              // 0/8/16/24
  for (int t = 0; t < nit; ++t) {
    if (t + 2 < nit) stage(cur == 0 ? 2 : cur - 1, (t + 2) << 5);
    {
      f16x8 af[4], bf[4];
#pragma unroll
      for (int mt = 0; mt < 4; ++mt) {
        int row = wm * 64 + mt * 16 + lr;
        af[mt] = *(const f16x8*)&lA[cur][(row << 5) + (kc ^ ((row & 3) << 3))];
      }
#pragma unroll
      for (int nt = 0; nt < 4; ++nt) {
        int row = wn * 64 + nt * 16 + lr;
        bf[nt] = *(const f16x8*)&lB[cur][(row << 5) + (kc ^ ((row & 3) << 3))];
      }
#pragma unroll
      for (int mt = 0; mt < 4; ++mt)
#pragma unroll
        for (int nt = 0; nt < 4; ++nt)
          acc[mt][nt] = MFMA16(af[mt], bf[nt], acc[mt][nt]);
    }
    if (t + 1 < nit) {
      if (t + 2 < nit) {
        // wait tile t+1 only; tile t+2's 4 loads stay in flight across barrier
        asm volatile("s_waitcnt vmcnt(4)" ::: "memory");
      } else {
        asm volatile("s_waitcnt vmcnt(0)" ::: "memory");
      }
      __builtin_amdgcn_s_barrier();
      __builtin_amdgcn_sched_barrier(0);
      cur = (cur == 2) ? 0 : cur + 1;
    }
  }

  if constexpr (QKV == 1) {
    if (z < 2) {
      // fused RMSNorm: wave's 64 cols == one head chunk
      const float* nw = z == 0 ? qnw : knw;
      f16* o = z == 0 ? oq : ok;
      const float eps = 1.1920929e-7f;
      const float osc = z == 0 ? 0.125f : 1.0f;  // fold attn 1/sqrt(D) into q
      float wv_[4];
#pragma unroll
      for (int nt = 0; nt < 4; ++nt) wv_[nt] = nw[nt * 16 + lr] * osc;
#pragma unroll
      for (int mt = 0; mt < 4; ++mt) {
        float vbuf[4][4];
        float ss[4] = {0.f, 0.f, 0.f, 0.f};
#pragma unroll
        for (int nt = 0; nt < 4; ++nt) {
          float bv = bias[n0 + wn * 64 + nt * 16 + lr];
#pragma unroll
          for (int i = 0; i < 4; ++i) {
            float v = acc[mt][nt][i] + bv;
            vbuf[nt][i] = v;
            ss[i] += v * v;
          }
        }
        float rr[4];
#pragma unroll
        for (int i = 0; i < 4; ++i) {
          ss[i] += __shfl_xor(ss[i], 1);
          ss[i] += __shfl_xor(ss[i], 2);
          ss[i] += __shfl_xor(ss[i], 4);
          ss[i] += __shfl_xor(ss[i], 8);
          rr[i] = rsqrtf(ss[i] * (1.0f / 64.0f) + eps);
        }
        int row = m0 + wm * 64 + mt * 16 + (lg << 2);
#pragma unroll
        for (int nt = 0; nt < 4; ++nt) {
          int col = n0 + wn * 64 + nt * 16 + lr;
#pragma unroll
          for (int i = 0; i < 4; ++i)
            o[(size_t)(row + i) * N + col] = (f16)(vbuf[nt][i] * rr[i] * wv_[nt]);
        }
      }
    } else {
      // fused V transpose: Vt[b][h][d][t], 4 contiguous t per store
#pragma unroll
      for (int mt = 0; mt < 4; ++mt) {
        int row = m0 + wm * 64 + mt * 16 + (lg << 2);
        int b = row >> 11;
        int t = row & (T - 1);
#pragma unroll
        for (int nt = 0; nt < 4; ++nt) {
          int col = n0 + wn * 64 + nt * 16 + lr;
          float bv = bias[col];
          int h = col >> 6, d = col & 63;
          f16x4 pk = {(f16)(acc[mt][nt][0] + bv), (f16)(acc[mt][nt][1] + bv),
                      (f16)(acc[mt][nt][2] + bv), (f16)(acc[mt][nt][3] + bv)};
          *(f16x4*)&Vt[(((size_t)(b * H + h) * D + d) << 11) + t] = pk;
        }
      }
    }
  } else {
#pragma unroll
    for (int mt = 0; mt < 4; ++mt) {
#pragma unroll
      for (int nt = 0; nt < 4; ++nt) {
        int row = m0 + wm * 64 + mt * 16 + (lg << 2);
        int col = n0 + wn * 64 + nt * 16 + lr;
        float bv = bias[col];
#pragma unroll
        for (int i = 0; i < 4; ++i)
          of32[(size_t)(row + i) * N + col] = acc[mt][nt][i] + bv;
      }
    }
  }
}

// ---------------- sliding-window flash attention ----------------
// grid (T/64, B*H), 4 waves; wave w owns 16 query rows; 64-key tiles.
// K/V staged via global_load_lds, 2-phase double-buffered across kt.
// Q pre-scaled by 0.125 in the QKV epilogue; mask only diagonal/tail tiles;
// defer-rescale skips fac work when max didn't grow.
__global__ __launch_bounds__(256) void attn_kernel(const f16* __restrict__ qn,
                                                   const f16* __restrict__ kn,
                                                   const f16* __restrict__ Vt,
                                                   f16* __restrict__ aout) {
  int q0 = blockIdx.x * 64;
  int bh = blockIdx.y;
  int b = bh >> 4, h = bh & 15;
  int tid = threadIdx.x;
  int w = tid >> 6, lane = tid & 63;
  int lr = lane & 15, lg = lane >> 4;

  __shared__ f16 lK[2][4096];
  __shared__ f16 lV[2][4096];
  __shared__ f16 lP[4096];

  const f16* Qb = qn + (size_t)(b * T + q0 + w * 16 + lr) * E + h * 64 + (lg << 3);
  f16x8 qf0 = *(const f16x8*)Qb;
  f16x8 qf1 = *(const f16x8*)(Qb + 32);

  f32x4 zero = {0.f, 0.f, 0.f, 0.f};
  f32x4 acc[4] = {zero, zero, zero, zero};
  float m[4] = {NEGF, NEGF, NEGF, NEGF};
  float l[4] = {0.f, 0.f, 0.f, 0.f};

  int mi = q0 >> 6;
  int kts = mi - 4 < 0 ? 0 : mi - 4;

  const f16* Kbase = kn + (size_t)b * T * E + h * 64;
  const f16* Vbase = Vt + (size_t)bh * D * T;

  int srow = lane >> 3;
  int scol = (lane & 7) << 3;

  auto stageKV = [&](int buf, int kt) {
    int k0 = kt << 6;
#pragma unroll
    for (int p = 0; p < 2; ++p) {
      int cc = (w << 1) + p;  // 8 calls cover 64x64 tile
      int row = (cc << 3) + srow;
      int gc = scol ^ ((row & 7) << 3);
      gload16(Kbase + (size_t)(k0 + row) * E + gc, &lK[buf][cc << 9]);
      gload16(Vbase + (size_t)row * T + k0 + gc, &lV[buf][cc << 9]);
    }
  };

  stageKV(0, kts);
  __syncthreads();
  int cur = 0;

  for (int kt = kts; kt <= mi; ++kt) {
    if (kt < mi) stageKV(cur ^ 1, kt + 1);
    int k0 = kt << 6;

    f32x4 s[4];
#pragma unroll
    for (int ct = 0; ct < 4; ++ct) s[ct] = zero;
#pragma unroll
    for (int kk = 0; kk < 2; ++kk) {
      int kc = kk * 32 + (lg << 3);
#pragma unroll
      for (int ct = 0; ct < 4; ++ct) {
        int row = ct * 16 + lr;
        f16x8 bf = *(const f16x8*)&lK[cur][((row << 6) + kc) ^ ((row & 7) << 3)];
        s[ct] = MFMA16(kk == 0 ? qf0 : qf1, bf, s[ct]);
      }
    }

    // mask (only diagonal / window-tail tiles) + row max
    float tm[4] = {NEGF, NEGF, NEGF, NEGF};
    int rowg0 = q0 + w * 16 + (lg << 2);
    bool needmask = (kt == mi) || (mi >= 4 && kt == kts);
    if (needmask) {
#pragma unroll
      for (int ct = 0; ct < 4; ++ct) {
        int col = k0 + ct * 16 + lr;
#pragma unroll
        for (int i = 0; i < 4; ++i) {
          int rowg = rowg0 + i;
          float v = s[ct][i];
          if (col > rowg || rowg - col >= WIN) v = NEGF;
          s[ct][i] = v;
          tm[i] = fmaxf(tm[i], v);
        }
      }
    } else {
#pragma unroll
      for (int ct = 0; ct < 4; ++ct)
#pragma unroll
        for (int i = 0; i < 4; ++i) tm[i] = fmaxf(tm[i], s[ct][i]);
    }
#pragma unroll
    for (int i = 0; i < 4; ++i) {
      tm[i] = fmaxf(tm[i], __shfl_xor(tm[i], 1));
      tm[i] = fmaxf(tm[i], __shfl_xor(tm[i], 2));
      tm[i] = fmaxf(tm[i], __shfl_xor(tm[i], 4));
      tm[i] = fmaxf(tm[i], __shfl_xor(tm[i], 8));
    }
    // defer-rescale: only pay fac when some row's max grew
    bool up = (tm[0] > m[0]) || (tm[1] > m[1]) || (tm[2] > m[2]) ||
              (tm[3] > m[3]);
    if (__any(up)) {
      float fac[4];
#pragma unroll
      for (int i = 0; i < 4; ++i) {
        float mn = fmaxf(m[i], tm[i]);
        fac[i] = exp2f((m[i] - mn) * L2E);
        m[i] = mn;
        l[i] *= fac[i];
      }
#pragma unroll
      for (int dt = 0; dt < 4; ++dt)
#pragma unroll
        for (int i = 0; i < 4; ++i) acc[dt][i] *= fac[i];
    }
    float ps[4] = {0.f, 0.f, 0.f, 0.f};
#pragma unroll
    for (int ct = 0; ct < 4; ++ct)
#pragma unroll
      for (int i = 0; i < 4; ++i) {
        float p = exp2f((s[ct][i] - m[i]) * L2E);
        s[ct][i] = p;
        ps[i] += p;
      }
#pragma unroll
    for (int i = 0; i < 4; ++i) {
      ps[i] += __shfl_xor(ps[i], 1);
      ps[i] += __shfl_xor(ps[i], 2);
      ps[i] += __shfl_xor(ps[i], 4);
      ps[i] += __shfl_xor(ps[i], 8);
      l[i] += ps[i];
    }

    // write P to per-wave LDS region in A-fragment-readable layout
#pragma unroll
    for (int ct = 0; ct < 4; ++ct)
#pragma unroll
      for (int i = 0; i < 4; ++i) {
        int qloc = (lg << 2) + i;
        int el = (qloc << 6) + ct * 16 + lr;
        lP[w * 1024 + (el ^ ((qloc & 7) << 3))] = (f16)s[ct][i];
      }

    // PV
#pragma unroll
    for (int kk = 0; kk < 2; ++kk) {
      int kc = kk * 32 + (lg << 3);
      int ep = w * 1024 + (((lr << 6) + kc) ^ ((lr & 7) << 3));
      f16x8 pf = *(const f16x8*)&lP[ep];
#pragma unroll
      for (int dt = 0; dt < 4; ++dt) {
        int row = dt * 16 + lr;
        f16x8 vf = *(const f16x8*)&lV[cur][((row << 6) + kc) ^ ((row & 7) << 3)];
        acc[dt] = MFMA16(pf, vf, acc[dt]);
      }
    }

    if (kt < mi) {
      __syncthreads();
      cur ^= 1;
    }
  }

#pragma unroll
  for (int i = 0; i < 4; ++i) {
    float inv = 1.0f / l[i];
    int tok = q0 + w * 16 + (lg << 2) + i;
    f16* dst = aout + (size_t)(b * T + tok) * E + h * 64 + lr;
#pragma unroll
    for (int dt = 0; dt < 4; ++dt) dst[dt * 16] = (f16)(acc[dt][i] * inv);
  }
}

// ---------------- launch ----------------
extern "C" void kernel_launch(void* const* d_in, const int* in_sizes, int n_in,
                              void* d_out, int out_size, void* d_ws,
                              size_t ws_size, hipStream_t stream) {
  const float* x = (const float*)d_in[0];
  const float* wq = (const float*)d_in[1];
  const float* bq = (const float*)d_in[2];
  const float* wk = (const float*)d_in[3];
  const float* bk = (const float*)d_in[4];
  const float* wv = (const float*)d_in[5];
  const float* bv = (const float*)d_in[6];
  const float* wo = (const float*)d_in[7];
  const float* bo = (const float*)d_in[8];
  const float* qn_w = (const float*)d_in[9];
  const float* kn_w = (const float*)d_in[10];
  float* out = (float*)d_out;

  char* ws = (char*)d_ws;
  const size_t MB = 1u << 20;
  f16* xb = (f16*)(ws);              // 8 MB
  f16* wqT = (f16*)(ws + 8 * MB);    // 2 MB
  f16* wkT = (f16*)(ws + 10 * MB);   // 2 MB
  f16* wvT = (f16*)(ws + 12 * MB);   // 2 MB
  f16* woT = (f16*)(ws + 14 * MB);   // 2 MB
  f16* qn = (f16*)(ws + 16 * MB);    // 8 MB
  f16* kn = (f16*)(ws + 24 * MB);    // 8 MB
  f16* Vt = (f16*)(ws + 32 * MB);    // 8 MB
  f16* aout = (f16*)(ws + 40 * MB);  // 8 MB

  cast_x_kernel<<<4096, 256, 0, stream>>>(x, xb);
  transpose_w_kernel<<<dim3(16, 16, 4), 256, 0, stream>>>(wq, wk, wv, wo, wqT,
                                                          wkT, wvT, woT);
  gemm_bt_kernel<1><<<dim3(32, 8, 3), 256, 0, stream>>>(
      xb, wqT, wkT, wvT, bq, bk, bv, qn_w, kn_w, qn, kn, Vt, nullptr, 4096,
      1024, 1024);
  attn_kernel<<<dim3(32, 32), 256, 0, stream>>>(qn, kn, Vt, aout);
  gemm_bt_kernel<0><<<dim3(32, 8, 1), 256, 0, stream>>>(
      aout, woT, woT, woT, bo, bo, bo, nullptr, nullptr, nullptr, nullptr,
      nullptr, out, 4096, 1024, 1024);
}

// Round 12
// 115.148 us; speedup vs baseline: 1.0358x; 1.0358x over previous
//
#include <hip/hip_runtime.h>

typedef _Float16 f16;
typedef _Float16 f16x4 __attribute__((ext_vector_type(4)));
typedef _Float16 f16x8 __attribute__((ext_vector_type(8)));
typedef float f32x4 __attribute__((ext_vector_type(4)));

#define MFMA16(a, b, c) __builtin_amdgcn_mfma_f32_16x16x32_f16(a, b, c, 0, 0, 0)

constexpr int T = 2048;
constexpr int E = 1024;
constexpr int H = 16;
constexpr int D = 64;
constexpr int WIN = 256;
#define NEGF (-1e30f)
#define L2E 1.4426950408889634f

// async global->LDS, 16B per lane; LDS base must be wave-uniform (HW: base + lane*16)
__device__ __forceinline__ void gload16(const f16* g, f16* l) {
  __builtin_amdgcn_global_load_lds(
      (__attribute__((address_space(1))) void*)(void*)g,
      (__attribute__((address_space(3))) void*)(void*)l, 16, 0, 0);
}

// ---------------- cast x (f32 -> f16) ----------------
__global__ __launch_bounds__(256) void cast_x_kernel(const float* __restrict__ x,
                                                     f16* __restrict__ xb) {
  int idx = (blockIdx.x * 256 + threadIdx.x) * 4;
  float4 v = *(const float4*)(x + idx);
  f16x4 o = {(f16)v.x, (f16)v.y, (f16)v.z, (f16)v.w};
  *(f16x4*)(xb + idx) = o;
}

// ---------------- transpose+cast weights: w[K,N] f32 -> wT[N,K] f16 ----------------
__global__ __launch_bounds__(256) void transpose_w_kernel(
    const float* __restrict__ w0, const float* __restrict__ w1,
    const float* __restrict__ w2, const float* __restrict__ w3,
    f16* __restrict__ o0, f16* __restrict__ o1, f16* __restrict__ o2,
    f16* __restrict__ o3) {
  int z = blockIdx.z;
  const float* w = z == 0 ? w0 : z == 1 ? w1 : z == 2 ? w2 : w3;
  f16* o = z == 0 ? o0 : z == 1 ? o1 : z == 2 ? o2 : o3;
  __shared__ float tile[64][65];
  int k0 = blockIdx.x * 64, n0 = blockIdx.y * 64;
  int r = threadIdx.x >> 2, cb = (threadIdx.x & 3) * 16;
  const float* src = w + (size_t)(k0 + r) * E + n0 + cb;
#pragma unroll
  for (int j = 0; j < 16; j += 4) {
    float4 v = *(const float4*)(src + j);
    tile[r][cb + j] = v.x;
    tile[r][cb + j + 1] = v.y;
    tile[r][cb + j + 2] = v.z;
    tile[r][cb + j + 3] = v.w;
  }
  __syncthreads();
  f16 tmp[16];
#pragma unroll
  for (int j = 0; j < 16; ++j) tmp[j] = (f16)tile[cb + j][r];
  f16* dst = o + (size_t)(n0 + r) * E + k0 + cb;
  *(f16x8*)dst = *(f16x8*)&tmp[0];
  *(f16x8*)(dst + 8) = *(f16x8*)&tmp[8];
}

// ---------------- fused QKV 256^2 deep-phase GEMM ----------------
// C[4096,3072] = X[4096,1024] @ Ball[3072,1024]^T, Ball = [wqT;wkT;wvT].
// 256x256 tile, BK=64, 8 waves (2M x 4N), per-wave 128x64 output.
// Per K-tile: phase A {stage B(t+1)->buf^1, ds_read kk0},
//             phase B {ds_read kk1, MFMA kk0},
//             mid-barrier [lgkmcnt(0); sched_barrier; s_barrier]  (buf reads done)
//             phase C {stage A(t+2)->buf, MFMA kk1},
//             entry barrier [vmcnt(4); s_barrier]  (A(t+2) stays in flight).
// Ledger: buf written only after the barrier ending its last read; tile t's 8
// loads (A: grp t-2 phase C, B: grp t-1 phase A) are >=2 phases old at the
// vmcnt(4) that precedes their consumption. Tail: vmcnt(0) when prefetch ends.
// Epilogue: z = by>>2 -> q/k RMSNorm (q folds 0.125), v transposed store.
__global__ __launch_bounds__(512) void qkv256_kernel(
    const f16* __restrict__ A, const f16* __restrict__ Ball,
    const float* __restrict__ cq, const float* __restrict__ ck,
    const float* __restrict__ cv, const float* __restrict__ qnw,
    const float* __restrict__ knw, f16* __restrict__ oq, f16* __restrict__ ok,
    f16* __restrict__ Vt) {
  const int K = E;
  __shared__ f16 lA[2][16384];  // 256x64 per buffer
  __shared__ f16 lB[2][16384];

  int m0 = blockIdx.x * 256;
  int nb = blockIdx.y;       // 0..11
  int n0 = nb * 256;         // row into Ball
  int tid = threadIdx.x;
  int wid = tid >> 6, lane = tid & 63;
  int wm = wid >> 2, wn = wid & 3;
  int lr = lane & 15, lg = lane >> 4;

  f32x4 zero = {0.f, 0.f, 0.f, 0.f};
  f32x4 acc[8][4];
#pragma unroll
  for (int a = 0; a < 8; ++a)
#pragma unroll
    for (int b = 0; b < 4; ++b) acc[a][b] = zero;

  int s8 = lane >> 3;        // row within 8-row stripe
  int c8 = (lane & 7) << 3;  // linear col (f16)

  auto stageA = [&](int t, int buf) {
#pragma unroll
    for (int c = 0; c < 4; ++c) {
      int row = (c << 6) + (wid << 3) + s8;
      int gc = c8 ^ ((row & 7) << 3);
      gload16(A + (size_t)(m0 + row) * K + (t << 6) + gc,
              &lA[buf][((c << 6) + (wid << 3)) << 6]);
    }
  };
  auto stageB = [&](int t, int buf) {
#pragma unroll
    for (int c = 0; c < 4; ++c) {
      int row = (c << 6) + (wid << 3) + s8;
      int gc = c8 ^ ((row & 7) << 3);
      gload16(Ball + (size_t)(n0 + row) * K + (t << 6) + gc,
              &lB[buf][((c << 6) + (wid << 3)) << 6]);
    }
  };

  // prologue: A(0),B(0) -> buf0; A(1) -> buf1
  stageA(0, 0);
  stageB(0, 0);
  stageA(1, 1);
  asm volatile("s_waitcnt vmcnt(4)" ::: "memory");  // A(0),B(0) landed
  __builtin_amdgcn_s_barrier();
  __builtin_amdgcn_sched_barrier(0);

  for (int t = 0; t < 16; ++t) {
    int buf = t & 1;
    // ---- phase A: stage B(t+1), ds_read kk0 ----
    if (t + 1 < 16) stageB(t + 1, buf ^ 1);
    f16x8 a0[8], b0[4], a1[8], b1[4];
#pragma unroll
    for (int mt = 0; mt < 8; ++mt) {
      int row = wm * 128 + mt * 16 + lr;
      a0[mt] =
          *(const f16x8*)&lA[buf][((row << 6) + (lg << 3)) ^ ((row & 7) << 3)];
    }
#pragma unroll
    for (int nt = 0; nt < 4; ++nt) {
      int row = wn * 64 + nt * 16 + lr;
      b0[nt] =
          *(const f16x8*)&lB[buf][((row << 6) + (lg << 3)) ^ ((row & 7) << 3)];
    }
    // ---- phase B: ds_read kk1 (issue first), MFMA kk0 ----
#pragma unroll
    for (int mt = 0; mt < 8; ++mt) {
      int row = wm * 128 + mt * 16 + lr;
      a1[mt] = *(const f16x8*)&lA[buf][((row << 6) + 32 + (lg << 3)) ^
                                       ((row & 7) << 3)];
    }
#pragma unroll
    for (int nt = 0; nt < 4; ++nt) {
      int row = wn * 64 + nt * 16 + lr;
      b1[nt] = *(const f16x8*)&lB[buf][((row << 6) + 32 + (lg << 3)) ^
                                       ((row & 7) << 3)];
    }
    __builtin_amdgcn_s_setprio(1);
#pragma unroll
    for (int mt = 0; mt < 8; ++mt)
#pragma unroll
      for (int nt = 0; nt < 4; ++nt)
        acc[mt][nt] = MFMA16(a0[mt], b0[nt], acc[mt][nt]);
    __builtin_amdgcn_s_setprio(0);
    // ---- mid barrier: all reads of buf complete chip-wide ----
    asm volatile("s_waitcnt lgkmcnt(0)" ::: "memory");
    __builtin_amdgcn_sched_barrier(0);
    __builtin_amdgcn_s_barrier();
    // ---- phase C: stage A(t+2) into buf (now writable), MFMA kk1 ----
    if (t + 2 < 16) stageA(t + 2, buf);
    __builtin_amdgcn_s_setprio(1);
#pragma unroll
    for (int mt = 0; mt < 8; ++mt)
#pragma unroll
      for (int nt = 0; nt < 4; ++nt)
        acc[mt][nt] = MFMA16(a1[mt], b1[nt], acc[mt][nt]);
    __builtin_amdgcn_s_setprio(0);
    // ---- entry barrier of next group: counted vmcnt ----
    if (t + 1 < 16) {
      if (t + 2 < 16)
        asm volatile("s_waitcnt vmcnt(4)" ::: "memory");  // A(t+2) in flight
      else
        asm volatile("s_waitcnt vmcnt(0)" ::: "memory");  // tail drain
      __builtin_amdgcn_s_barrier();
      __builtin_amdgcn_sched_barrier(0);
    }
  }

  // ---- epilogue ----
  int z = nb >> 2;
  int n0z = (nb & 3) * 256;
  const float eps = 1.1920929e-7f;
  if (z < 2) {
    const float* nw = z == 0 ? qnw : knw;
    const float* bias = z == 0 ? cq : ck;
    f16* o = z == 0 ? oq : ok;
    const float osc = z == 0 ? 0.125f : 1.0f;  // fold attn 1/sqrt(D) into q
    float wv_[4];
#pragma unroll
    for (int nt = 0; nt < 4; ++nt) wv_[nt] = nw[nt * 16 + lr] * osc;
#pragma unroll
    for (int mt = 0; mt < 8; ++mt) {
      float vbuf[4][4];
      float ss[4] = {0.f, 0.f, 0.f, 0.f};
#pragma unroll
      for (int nt = 0; nt < 4; ++nt) {
        float bv = bias[n0z + wn * 64 + nt * 16 + lr];
#pragma unroll
        for (int i = 0; i < 4; ++i) {
          float v = acc[mt][nt][i] + bv;
          vbuf[nt][i] = v;
          ss[i] += v * v;
        }
      }
      float rr[4];
#pragma unroll
      for (int i = 0; i < 4; ++i) {
        ss[i] += __shfl_xor(ss[i], 1);
        ss[i] += __shfl_xor(ss[i], 2);
        ss[i] += __shfl_xor(ss[i], 4);
        ss[i] += __shfl_xor(ss[i], 8);
        rr[i] = rsqrtf(ss[i] * (1.0f / 64.0f) + eps);
      }
      int row = m0 + wm * 128 + mt * 16 + (lg << 2);
#pragma unroll
      for (int nt = 0; nt < 4; ++nt) {
        int col = n0z + wn * 64 + nt * 16 + lr;
#pragma unroll
        for (int i = 0; i < 4; ++i)
          o[(size_t)(row + i) * E + col] = (f16)(vbuf[nt][i] * rr[i] * wv_[nt]);
      }
    }
  } else {
    // v: transposed store Vt[b][h][d][t]
#pragma unroll
    for (int mt = 0; mt < 8; ++mt) {
      int row = m0 + wm * 128 + mt * 16 + (lg << 2);
      int b = row >> 11;
      int tt = row & (T - 1);
#pragma unroll
      for (int nt = 0; nt < 4; ++nt) {
        int col = n0z + wn * 64 + nt * 16 + lr;
        float bv = cv[col];
        int h = col >> 6, d = col & 63;
        f16x4 pk = {(f16)(acc[mt][nt][0] + bv), (f16)(acc[mt][nt][1] + bv),
                    (f16)(acc[mt][nt][2] + bv), (f16)(acc[mt][nt][3] + bv)};
        *(f16x4*)&Vt[(((size_t)(b * H + h) * D + d) << 11) + tt] = pk;
      }
    }
  }
}

// ---------------- out GEMM (R7-proven): 128x128, BK=64, 2-phase dbuf ----------------
__global__ __launch_bounds__(256) void out_gemm_kernel(
    const f16* __restrict__ A, const f16* __restrict__ Bt,
    const float* __restrict__ bias, float* __restrict__ out, int M, int N,
    int K) {
  __shared__ f16 lA[2][8192];
  __shared__ f16 lB[2][8192];

  int m0 = blockIdx.x * 128, n0 = blockIdx.y * 128;
  int tid = threadIdx.x;
  int wid = tid >> 6, lane = tid & 63;
  int wm = wid >> 1, wn = wid & 1;
  int lr = lane & 15, lg = lane >> 4;

  f32x4 zero = {0.f, 0.f, 0.f, 0.f};
  f32x4 acc[4][4];
  for (int a = 0; a < 4; ++a)
    for (int b = 0; b < 4; ++b) acc[a][b] = zero;

  int srow = lane >> 3;
  int scol = (lane & 7) << 3;

  auto stage = [&](int buf, int k0) {
#pragma unroll
    for (int p = 0; p < 4; ++p) {
      int cc = (wid << 2) + p;
      int row = (cc << 3) + srow;
      int gc = scol ^ ((row & 7) << 3);
      gload16(A + (size_t)(m0 + row) * K + k0 + gc, &lA[buf][cc << 9]);
      gload16(Bt + (size_t)(n0 + row) * K + k0 + gc, &lB[buf][cc << 9]);
    }
  };

  int nit = K >> 6;
  stage(0, 0);
  __syncthreads();
  int cur = 0;
  for (int t = 0; t < nit; ++t) {
    if (t + 1 < nit) stage(cur ^ 1, (t + 1) << 6);
#pragma unroll
    for (int kk = 0; kk < 2; ++kk) {
      int kc = kk * 32 + (lg << 3);
      f16x8 af[4], bf[4];
#pragma unroll
      for (int mt = 0; mt < 4; ++mt) {
        int row = wm * 64 + mt * 16 + lr;
        af[mt] = *(const f16x8*)&lA[cur][((row << 6) + kc) ^ ((row & 7) << 3)];
      }
#pragma unroll
      for (int nt = 0; nt < 4; ++nt) {
        int row = wn * 64 + nt * 16 + lr;
        bf[nt] = *(const f16x8*)&lB[cur][((row << 6) + kc) ^ ((row & 7) << 3)];
      }
#pragma unroll
      for (int mt = 0; mt < 4; ++mt)
#pragma unroll
        for (int nt = 0; nt < 4; ++nt)
          acc[mt][nt] = MFMA16(af[mt], bf[nt], acc[mt][nt]);
    }
    if (t + 1 < nit) {
      __syncthreads();
      cur ^= 1;
    }
  }

#pragma unroll
  for (int mt = 0; mt < 4; ++mt) {
#pragma unroll
    for (int nt = 0; nt < 4; ++nt) {
      int row = m0 + wm * 64 + mt * 16 + (lg << 2);
      int col = n0 + wn * 64 + nt * 16 + lr;
      float bv = bias[col];
#pragma unroll
      for (int i = 0; i < 4; ++i)
        out[(size_t)(row + i) * N + col] = acc[mt][nt][i] + bv;
    }
  }
}

// ---------------- sliding-window flash attention ----------------
// grid (T/64, B*H), 4 waves; wave w owns 16 query rows; 64-key tiles.
// K/V staged via global_load_lds, 2-phase double-buffered across kt.
// Q pre-scaled by 0.125 in the QKV epilogue; mask only diagonal/tail tiles;
// defer-rescale skips fac work when max didn't grow.
__global__ __launch_bounds__(256) void attn_kernel(const f16* __restrict__ qn,
                                                   const f16* __restrict__ kn,
                                                   const f16* __restrict__ Vt,
                                                   f16* __restrict__ aout) {
  int q0 = blockIdx.x * 64;
  int bh = blockIdx.y;
  int b = bh >> 4, h = bh & 15;
  int tid = threadIdx.x;
  int w = tid >> 6, lane = tid & 63;
  int lr = lane & 15, lg = lane >> 4;

  __shared__ f16 lK[2][4096];
  __shared__ f16 lV[2][4096];
  __shared__ f16 lP[4096];

  const f16* Qb = qn + (size_t)(b * T + q0 + w * 16 + lr) * E + h * 64 + (lg << 3);
  f16x8 qf0 = *(const f16x8*)Qb;
  f16x8 qf1 = *(const f16x8*)(Qb + 32);

  f32x4 zero = {0.f, 0.f, 0.f, 0.f};
  f32x4 acc[4] = {zero, zero, zero, zero};
  float m[4] = {NEGF, NEGF, NEGF, NEGF};
  float l[4] = {0.f, 0.f, 0.f, 0.f};

  int mi = q0 >> 6;
  int kts = mi - 4 < 0 ? 0 : mi - 4;

  const f16* Kbase = kn + (size_t)b * T * E + h * 64;
  const f16* Vbase = Vt + (size_t)bh * D * T;

  int srow = lane >> 3;
  int scol = (lane & 7) << 3;

  auto stageKV = [&](int buf, int kt) {
    int k0 = kt << 6;
#pragma unroll
    for (int p = 0; p < 2; ++p) {
      int cc = (w << 1) + p;  // 8 calls cover 64x64 tile
      int row = (cc << 3) + srow;
      int gc = scol ^ ((row & 7) << 3);
      gload16(Kbase + (size_t)(k0 + row) * E + gc, &lK[buf][cc << 9]);
      gload16(Vbase + (size_t)row * T + k0 + gc, &lV[buf][cc << 9]);
    }
  };

  stageKV(0, kts);
  __syncthreads();
  int cur = 0;

  for (int kt = kts; kt <= mi; ++kt) {
    if (kt < mi) stageKV(cur ^ 1, kt + 1);
    int k0 = kt << 6;

    f32x4 s[4];
#pragma unroll
    for (int ct = 0; ct < 4; ++ct) s[ct] = zero;
#pragma unroll
    for (int kk = 0; kk < 2; ++kk) {
      int kc = kk * 32 + (lg << 3);
#pragma unroll
      for (int ct = 0; ct < 4; ++ct) {
        int row = ct * 16 + lr;
        f16x8 bf = *(const f16x8*)&lK[cur][((row << 6) + kc) ^ ((row & 7) << 3)];
        s[ct] = MFMA16(kk == 0 ? qf0 : qf1, bf, s[ct]);
      }
    }

    // mask (only diagonal / window-tail tiles) + row max
    float tm[4] = {NEGF, NEGF, NEGF, NEGF};
    int rowg0 = q0 + w * 16 + (lg << 2);
    bool needmask = (kt == mi) || (mi >= 4 && kt == kts);
    if (needmask) {
#pragma unroll
      for (int ct = 0; ct < 4; ++ct) {
        int col = k0 + ct * 16 + lr;
#pragma unroll
        for (int i = 0; i < 4; ++i) {
          int rowg = rowg0 + i;
          float v = s[ct][i];
          if (col > rowg || rowg - col >= WIN) v = NEGF;
          s[ct][i] = v;
          tm[i] = fmaxf(tm[i], v);
        }
      }
    } else {
#pragma unroll
      for (int ct = 0; ct < 4; ++ct)
#pragma unroll
        for (int i = 0; i < 4; ++i) tm[i] = fmaxf(tm[i], s[ct][i]);
    }
#pragma unroll
    for (int i = 0; i < 4; ++i) {
      tm[i] = fmaxf(tm[i], __shfl_xor(tm[i], 1));
      tm[i] = fmaxf(tm[i], __shfl_xor(tm[i], 2));
      tm[i] = fmaxf(tm[i], __shfl_xor(tm[i], 4));
      tm[i] = fmaxf(tm[i], __shfl_xor(tm[i], 8));
    }
    // defer-rescale: only pay fac when some row's max grew
    bool up = (tm[0] > m[0]) || (tm[1] > m[1]) || (tm[2] > m[2]) ||
              (tm[3] > m[3]);
    if (__any(up)) {
      float fac[4];
#pragma unroll
      for (int i = 0; i < 4; ++i) {
        float mn = fmaxf(m[i], tm[i]);
        fac[i] = exp2f((m[i] - mn) * L2E);
        m[i] = mn;
        l[i] *= fac[i];
      }
#pragma unroll
      for (int dt = 0; dt < 4; ++dt)
#pragma unroll
        for (int i = 0; i < 4; ++i) acc[dt][i] *= fac[i];
    }
    float ps[4] = {0.f, 0.f, 0.f, 0.f};
#pragma unroll
    for (int ct = 0; ct < 4; ++ct)
#pragma unroll
      for (int i = 0; i < 4; ++i) {
        float p = exp2f((s[ct][i] - m[i]) * L2E);
        s[ct][i] = p;
        ps[i] += p;
      }
#pragma unroll
    for (int i = 0; i < 4; ++i) {
      ps[i] += __shfl_xor(ps[i], 1);
      ps[i] += __shfl_xor(ps[i], 2);
      ps[i] += __shfl_xor(ps[i], 4);
      ps[i] += __shfl_xor(ps[i], 8);
      l[i] += ps[i];
    }

    // write P to per-wave LDS region in A-fragment-readable layout
#pragma unroll
    for (int ct = 0; ct < 4; ++ct)
#pragma unroll
      for (int i = 0; i < 4; ++i) {
        int qloc = (lg << 2) + i;
        int el = (qloc << 6) + ct * 16 + lr;
        lP[w * 1024 + (el ^ ((qloc & 7) << 3))] = (f16)s[ct][i];
      }

    // PV
#pragma unroll
    for (int kk = 0; kk < 2; ++kk) {
      int kc = kk * 32 + (lg << 3);
      int ep = w * 1024 + (((lr << 6) + kc) ^ ((lr & 7) << 3));
      f16x8 pf = *(const f16x8*)&lP[ep];
#pragma unroll
      for (int dt = 0; dt < 4; ++dt) {
        int row = dt * 16 + lr;
        f16x8 vf = *(const f16x8*)&lV[cur][((row << 6) + kc) ^ ((row & 7) << 3)];
        acc[dt] = MFMA16(pf, vf, acc[dt]);
      }
    }

    if (kt < mi) {
      __syncthreads();
      cur ^= 1;
    }
  }

#pragma unroll
  for (int i = 0; i < 4; ++i) {
    float inv = 1.0f / l[i];
    int tok = q0 + w * 16 + (lg << 2) + i;
    f16* dst = aout + (size_t)(b * T + tok) * E + h * 64 + lr;
#pragma unroll
    for (int dt = 0; dt < 4; ++dt) dst[dt * 16] = (f16)(acc[dt][i] * inv);
  }
}

// ---------------- launch ----------------
extern "C" void kernel_launch(void* const* d_in, const int* in_sizes, int n_in,
                              void* d_out, int out_size, void* d_ws,
                              size_t ws_size, hipStream_t stream) {
  const float* x = (const float*)d_in[0];
  const float* wq = (const float*)d_in[1];
  const float* bq = (const float*)d_in[2];
  const float* wk = (const float*)d_in[3];
  const float* bk = (const float*)d_in[4];
  const float* wv = (const float*)d_in[5];
  const float* bv = (const float*)d_in[6];
  const float* wo = (const float*)d_in[7];
  const float* bo = (const float*)d_in[8];
  const float* qn_w = (const float*)d_in[9];
  const float* kn_w = (const float*)d_in[10];
  float* out = (float*)d_out;

  char* ws = (char*)d_ws;
  const size_t MB = 1u << 20;
  f16* xb = (f16*)(ws);              // 8 MB
  f16* wAll = (f16*)(ws + 8 * MB);   // 6 MB: wqT | wkT | wvT contiguous
  f16* wqT = wAll;
  f16* wkT = wAll + (size_t)E * E;
  f16* wvT = wAll + 2 * (size_t)E * E;
  f16* woT = (f16*)(ws + 14 * MB);   // 2 MB
  f16* qn = (f16*)(ws + 16 * MB);    // 8 MB
  f16* kn = (f16*)(ws + 24 * MB);    // 8 MB
  f16* Vt = (f16*)(ws + 32 * MB);    // 8 MB
  f16* aout = (f16*)(ws + 40 * MB);  // 8 MB

  cast_x_kernel<<<4096, 256, 0, stream>>>(x, xb);
  transpose_w_kernel<<<dim3(16, 16, 4), 256, 0, stream>>>(wq, wk, wv, wo, wqT,
                                                          wkT, wvT, woT);
  qkv256_kernel<<<dim3(16, 12), 512, 0, stream>>>(xb, wAll, bq, bk, bv, qn_w,
                                                  kn_w, qn, kn, Vt);
  attn_kernel<<<dim3(32, 32), 256, 0, stream>>>(qn, kn, Vt, aout);
  out_gemm_kernel<<<dim3(32, 8), 256, 0, stream>>>(aout, woT, bo, out, 4096,
                                                   1024, 1024);
}

// Round 14
// 105.743 us; speedup vs baseline: 1.1279x; 1.0889x over previous
//
#include <hip/hip_runtime.h>

typedef _Float16 f16;
typedef _Float16 f16x4 __attribute__((ext_vector_type(4)));
typedef _Float16 f16x8 __attribute__((ext_vector_type(8)));
typedef float f32x4 __attribute__((ext_vector_type(4)));

#define MFMA16(a, b, c) __builtin_amdgcn_mfma_f32_16x16x32_f16(a, b, c, 0, 0, 0)

constexpr int T = 2048;
constexpr int E = 1024;
constexpr int H = 16;
constexpr int D = 64;
constexpr int WIN = 256;
#define NEGF (-1e30f)
#define L2E 1.4426950408889634f

// async global->LDS, 16B per lane; LDS base must be wave-uniform (HW: base + lane*16)
__device__ __forceinline__ void gload16(const f16* g, f16* l) {
  __builtin_amdgcn_global_load_lds(
      (__attribute__((address_space(1))) void*)(void*)g,
      (__attribute__((address_space(3))) void*)(void*)l, 16, 0, 0);
}

// ---------------- cast x (f32 -> f16) ----------------
__global__ __launch_bounds__(256) void cast_x_kernel(const float* __restrict__ x,
                                                     f16* __restrict__ xb) {
  int idx = (blockIdx.x * 256 + threadIdx.x) * 4;
  float4 v = *(const float4*)(x + idx);
  f16x4 o = {(f16)v.x, (f16)v.y, (f16)v.z, (f16)v.w};
  *(f16x4*)(xb + idx) = o;
}

// ---------------- transpose+cast weights: w[K,N] f32 -> wT[N,K] f16 ----------------
__global__ __launch_bounds__(256) void transpose_w_kernel(
    const float* __restrict__ w0, const float* __restrict__ w1,
    const float* __restrict__ w2, const float* __restrict__ w3,
    f16* __restrict__ o0, f16* __restrict__ o1, f16* __restrict__ o2,
    f16* __restrict__ o3) {
  int z = blockIdx.z;
  const float* w = z == 0 ? w0 : z == 1 ? w1 : z == 2 ? w2 : w3;
  f16* o = z == 0 ? o0 : z == 1 ? o1 : z == 2 ? o2 : o3;
  __shared__ float tile[64][65];
  int k0 = blockIdx.x * 64, n0 = blockIdx.y * 64;
  int r = threadIdx.x >> 2, cb = (threadIdx.x & 3) * 16;
  const float* src = w + (size_t)(k0 + r) * E + n0 + cb;
#pragma unroll
  for (int j = 0; j < 16; j += 4) {
    float4 v = *(const float4*)(src + j);
    tile[r][cb + j] = v.x;
    tile[r][cb + j + 1] = v.y;
    tile[r][cb + j + 2] = v.z;
    tile[r][cb + j + 3] = v.w;
  }
  __syncthreads();
  f16 tmp[16];
#pragma unroll
  for (int j = 0; j < 16; ++j) tmp[j] = (f16)tile[cb + j][r];
  f16* dst = o + (size_t)(n0 + r) * E + k0 + cb;
  *(f16x8*)dst = *(f16x8*)&tmp[0];
  *(f16x8*)(dst + 8) = *(f16x8*)&tmp[8];
}

// ---------------- GEMM: C[M,N] = A[M,K] * Bt[N,K]^T + bias ----------------
// R6-measured structure (44us QKV): 128x128 tile, BK=64, 4 waves, 2-phase
// dbuf, one __syncthreads per K-step. XCD-aware bijective swizzle: grid is
// 1-D (256 blocks); sw=(bid%8)*32+bid/8 gives each XCD a contiguous
// 4-mrow x 8-ncol chunk -> B panels fetched once per XCD L2, A 4x reuse.
// QKV=1: z=0/1 -> fused RMSNorm epilogue (q folds 0.125), z=2 -> V-transpose.
// QKV=0: plain f32 + bias epilogue.
template <int QKV>
__global__ __launch_bounds__(256) void gemm_bt_kernel(
    const f16* __restrict__ A, const f16* __restrict__ B0,
    const f16* __restrict__ B1, const f16* __restrict__ B2,
    const float* __restrict__ c0, const float* __restrict__ c1,
    const float* __restrict__ c2, const float* __restrict__ qnw,
    const float* __restrict__ knw, f16* __restrict__ oq, f16* __restrict__ ok,
    f16* __restrict__ Vt, float* __restrict__ of32, int M, int N, int K) {
  int z = blockIdx.z;
  const f16* Bt = z == 0 ? B0 : z == 1 ? B1 : B2;
  const float* bias = z == 0 ? c0 : z == 1 ? c1 : c2;

  __shared__ f16 lA[2][8192];
  __shared__ f16 lB[2][8192];

  // XCD swizzle (bijective, 256 % 8 == 0): chunk of 32 consecutive work ids
  // (4 m-rows x all 8 n-cols) lands on one XCD.
  int sw = ((blockIdx.x & 7) << 5) + (blockIdx.x >> 3);
  int m0 = (sw >> 3) << 7, n0 = (sw & 7) << 7;

  int tid = threadIdx.x;
  int wid = tid >> 6, lane = tid & 63;
  int wm = wid >> 1, wn = wid & 1;
  int lr = lane & 15, lg = lane >> 4;

  f32x4 zero = {0.f, 0.f, 0.f, 0.f};
  f32x4 acc[4][4];
  for (int a = 0; a < 4; ++a)
    for (int b = 0; b < 4; ++b) acc[a][b] = zero;

  // per-lane staging geometry (constant across K-steps)
  int srow = lane >> 3;          // sub-row within 8-row stripe of one call
  int scol = (lane & 7) << 3;    // linear col (f16 units)

  auto stage = [&](int buf, int k0) {
#pragma unroll
    for (int p = 0; p < 4; ++p) {
      int cc = (wid << 2) + p;   // 16 calls cover 128x64 tile
      int row = (cc << 3) + srow;
      int gc = scol ^ ((row & 7) << 3);  // inverse-swizzled source col
      gload16(A + (size_t)(m0 + row) * K + k0 + gc, &lA[buf][cc << 9]);
      gload16(Bt + (size_t)(n0 + row) * K + k0 + gc, &lB[buf][cc << 9]);
    }
  };

  int nit = K >> 6;
  stage(0, 0);
  __syncthreads();
  int cur = 0;
  for (int t = 0; t < nit; ++t) {
    if (t + 1 < nit) stage(cur ^ 1, (t + 1) << 6);
#pragma unroll
    for (int kk = 0; kk < 2; ++kk) {
      int kc = kk * 32 + (lg << 3);
      f16x8 af[4], bf[4];
#pragma unroll
      for (int mt = 0; mt < 4; ++mt) {
        int row = wm * 64 + mt * 16 + lr;
        af[mt] = *(const f16x8*)&lA[cur][((row << 6) + kc) ^ ((row & 7) << 3)];
      }
#pragma unroll
      for (int nt = 0; nt < 4; ++nt) {
        int row = wn * 64 + nt * 16 + lr;
        bf[nt] = *(const f16x8*)&lB[cur][((row << 6) + kc) ^ ((row & 7) << 3)];
      }
#pragma unroll
      for (int mt = 0; mt < 4; ++mt)
#pragma unroll
        for (int nt = 0; nt < 4; ++nt)
          acc[mt][nt] = MFMA16(af[mt], bf[nt], acc[mt][nt]);
    }
    if (t + 1 < nit) {
      __syncthreads();
      cur ^= 1;
    }
  }

  if constexpr (QKV == 1) {
    if (z < 2) {
      // fused RMSNorm: wave's 64 cols == one head chunk
      const float* nw = z == 0 ? qnw : knw;
      f16* o = z == 0 ? oq : ok;
      const float eps = 1.1920929e-7f;
      const float osc = z == 0 ? 0.125f : 1.0f;  // fold attn 1/sqrt(D) into q
      float wv_[4];
#pragma unroll
      for (int nt = 0; nt < 4; ++nt) wv_[nt] = nw[nt * 16 + lr] * osc;
#pragma unroll
      for (int mt = 0; mt < 4; ++mt) {
        float vbuf[4][4];
        float ss[4] = {0.f, 0.f, 0.f, 0.f};
#pragma unroll
        for (int nt = 0; nt < 4; ++nt) {
          float bv = bias[n0 + wn * 64 + nt * 16 + lr];
#pragma unroll
          for (int i = 0; i < 4; ++i) {
            float v = acc[mt][nt][i] + bv;
            vbuf[nt][i] = v;
            ss[i] += v * v;
          }
        }
        float rr[4];
#pragma unroll
        for (int i = 0; i < 4; ++i) {
          ss[i] += __shfl_xor(ss[i], 1);
          ss[i] += __shfl_xor(ss[i], 2);
          ss[i] += __shfl_xor(ss[i], 4);
          ss[i] += __shfl_xor(ss[i], 8);
          rr[i] = rsqrtf(ss[i] * (1.0f / 64.0f) + eps);
        }
        int row = m0 + wm * 64 + mt * 16 + (lg << 2);
#pragma unroll
        for (int nt = 0; nt < 4; ++nt) {
          int col = n0 + wn * 64 + nt * 16 + lr;
#pragma unroll
          for (int i = 0; i < 4; ++i)
            o[(size_t)(row + i) * N + col] = (f16)(vbuf[nt][i] * rr[i] * wv_[nt]);
        }
      }
    } else {
      // fused V transpose: Vt[b][h][d][t], 4 contiguous t per store
#pragma unroll
      for (int mt = 0; mt < 4; ++mt) {
        int row = m0 + wm * 64 + mt * 16 + (lg << 2);
        int b = row >> 11;
        int t = row & (T - 1);
#pragma unroll
        for (int nt = 0; nt < 4; ++nt) {
          int col = n0 + wn * 64 + nt * 16 + lr;
          float bv = bias[col];
          int h = col >> 6, d = col & 63;
          f16x4 pk = {(f16)(acc[mt][nt][0] + bv), (f16)(acc[mt][nt][1] + bv),
                      (f16)(acc[mt][nt][2] + bv), (f16)(acc[mt][nt][3] + bv)};
          *(f16x4*)&Vt[(((size_t)(b * H + h) * D + d) << 11) + t] = pk;
        }
      }
    }
  } else {
#pragma unroll
    for (int mt = 0; mt < 4; ++mt) {
#pragma unroll
      for (int nt = 0; nt < 4; ++nt) {
        int row = m0 + wm * 64 + mt * 16 + (lg << 2);
        int col = n0 + wn * 64 + nt * 16 + lr;
        float bv = bias[col];
#pragma unroll
        for (int i = 0; i < 4; ++i)
          of32[(size_t)(row + i) * N + col] = acc[mt][nt][i] + bv;
      }
    }
  }
}

// ---------------- sliding-window flash attention ----------------
// 1-D grid (1024 blocks), XCD swizzle: 128 consecutive work ids (= 4 complete
// bh, K/V ~2MB) per XCD -> K/V panels L2-resident per XCD.
// 4 waves; wave w owns 16 query rows; 64-key tiles; K/V via global_load_lds,
// 2-phase dbuf across kt. Q pre-scaled by 0.125; mask only diagonal/tail
// tiles; defer-rescale skips fac work when max didn't grow.
__global__ __launch_bounds__(256) void attn_kernel(const f16* __restrict__ qn,
                                                   const f16* __restrict__ kn,
                                                   const f16* __restrict__ Vt,
                                                   f16* __restrict__ aout) {
  int sw = ((blockIdx.x & 7) << 7) + (blockIdx.x >> 3);
  int q0 = (sw & 31) << 6;
  int bh = sw >> 5;
  int b = bh >> 4, h = bh & 15;
  int tid = threadIdx.x;
  int w = tid >> 6, lane = tid & 63;
  int lr = lane & 15, lg = lane >> 4;

  __shared__ f16 lK[2][4096];
  __shared__ f16 lV[2][4096];
  __shared__ f16 lP[4096];

  const f16* Qb = qn + (size_t)(b * T + q0 + w * 16 + lr) * E + h * 64 + (lg << 3);
  f16x8 qf0 = *(const f16x8*)Qb;
  f16x8 qf1 = *(const f16x8*)(Qb + 32);

  f32x4 zero = {0.f, 0.f, 0.f, 0.f};
  f32x4 acc[4] = {zero, zero, zero, zero};
  float m[4] = {NEGF, NEGF, NEGF, NEGF};
  float l[4] = {0.f, 0.f, 0.f, 0.f};

  int mi = q0 >> 6;
  int kts = mi - 4 < 0 ? 0 : mi - 4;

  const f16* Kbase = kn + (size_t)b * T * E + h * 64;
  const f16* Vbase = Vt + (size_t)bh * D * T;

  int srow = lane >> 3;
  int scol = (lane & 7) << 3;

  auto stageKV = [&](int buf, int kt) {
    int k0 = kt << 6;
#pragma unroll
    for (int p = 0; p < 2; ++p) {
      int cc = (w << 1) + p;  // 8 calls cover 64x64 tile
      int row = (cc << 3) + srow;
      int gc = scol ^ ((row & 7) << 3);
      gload16(Kbase + (size_t)(k0 + row) * E + gc, &lK[buf][cc << 9]);
      gload16(Vbase + (size_t)row * T + k0 + gc, &lV[buf][cc << 9]);
    }
  };

  stageKV(0, kts);
  __syncthreads();
  int cur = 0;

  for (int kt = kts; kt <= mi; ++kt) {
    if (kt < mi) stageKV(cur ^ 1, kt + 1);
    int k0 = kt << 6;

    f32x4 s[4];
#pragma unroll
    for (int ct = 0; ct < 4; ++ct) s[ct] = zero;
#pragma unroll
    for (int kk = 0; kk < 2; ++kk) {
      int kc = kk * 32 + (lg << 3);
#pragma unroll
      for (int ct = 0; ct < 4; ++ct) {
        int row = ct * 16 + lr;
        f16x8 bf = *(const f16x8*)&lK[cur][((row << 6) + kc) ^ ((row & 7) << 3)];
        s[ct] = MFMA16(kk == 0 ? qf0 : qf1, bf, s[ct]);
      }
    }

    // mask (only diagonal / window-tail tiles) + row max
    float tm[4] = {NEGF, NEGF, NEGF, NEGF};
    int rowg0 = q0 + w * 16 + (lg << 2);
    bool needmask = (kt == mi) || (mi >= 4 && kt == kts);
    if (needmask) {
#pragma unroll
      for (int ct = 0; ct < 4; ++ct) {
        int col = k0 + ct * 16 + lr;
#pragma unroll
        for (int i = 0; i < 4; ++i) {
          int rowg = rowg0 + i;
          float v = s[ct][i];
          if (col > rowg || rowg - col >= WIN) v = NEGF;
          s[ct][i] = v;
          tm[i] = fmaxf(tm[i], v);
        }
      }
    } else {
#pragma unroll
      for (int ct = 0; ct < 4; ++ct)
#pragma unroll
        for (int i = 0; i < 4; ++i) tm[i] = fmaxf(tm[i], s[ct][i]);
    }
#pragma unroll
    for (int i = 0; i < 4; ++i) {
      tm[i] = fmaxf(tm[i], __shfl_xor(tm[i], 1));
      tm[i] = fmaxf(tm[i], __shfl_xor(tm[i], 2));
      tm[i] = fmaxf(tm[i], __shfl_xor(tm[i], 4));
      tm[i] = fmaxf(tm[i], __shfl_xor(tm[i], 8));
    }
    // defer-rescale: only pay fac when some row's max grew
    bool up = (tm[0] > m[0]) || (tm[1] > m[1]) || (tm[2] > m[2]) ||
              (tm[3] > m[3]);
    if (__any(up)) {
      float fac[4];
#pragma unroll
      for (int i = 0; i < 4; ++i) {
        float mn = fmaxf(m[i], tm[i]);
        fac[i] = exp2f((m[i] - mn) * L2E);
        m[i] = mn;
        l[i] *= fac[i];
      }
#pragma unroll
      for (int dt = 0; dt < 4; ++dt)
#pragma unroll
        for (int i = 0; i < 4; ++i) acc[dt][i] *= fac[i];
    }
    float ps[4] = {0.f, 0.f, 0.f, 0.f};
#pragma unroll
    for (int ct = 0; ct < 4; ++ct)
#pragma unroll
      for (int i = 0; i < 4; ++i) {
        float p = exp2f((s[ct][i] - m[i]) * L2E);
        s[ct][i] = p;
        ps[i] += p;
      }
#pragma unroll
    for (int i = 0; i < 4; ++i) {
      ps[i] += __shfl_xor(ps[i], 1);
      ps[i] += __shfl_xor(ps[i], 2);
      ps[i] += __shfl_xor(ps[i], 4);
      ps[i] += __shfl_xor(ps[i], 8);
      l[i] += ps[i];
    }

    // write P to per-wave LDS region in A-fragment-readable layout
#pragma unroll
    for (int ct = 0; ct < 4; ++ct)
#pragma unroll
      for (int i = 0; i < 4; ++i) {
        int qloc = (lg << 2) + i;
        int el = (qloc << 6) + ct * 16 + lr;
        lP[w * 1024 + (el ^ ((qloc & 7) << 3))] = (f16)s[ct][i];
      }

    // PV
#pragma unroll
    for (int kk = 0; kk < 2; ++kk) {
      int kc = kk * 32 + (lg << 3);
      int ep = w * 1024 + (((lr << 6) + kc) ^ ((lr & 7) << 3));
      f16x8 pf = *(const f16x8*)&lP[ep];
#pragma unroll
      for (int dt = 0; dt < 4; ++dt) {
        int row = dt * 16 + lr;
        f16x8 vf = *(const f16x8*)&lV[cur][((row << 6) + kc) ^ ((row & 7) << 3)];
        acc[dt] = MFMA16(pf, vf, acc[dt]);
      }
    }

    if (kt < mi) {
      __syncthreads();
      cur ^= 1;
    }
  }

#pragma unroll
  for (int i = 0; i < 4; ++i) {
    float inv = 1.0f / l[i];
    int tok = q0 + w * 16 + (lg << 2) + i;
    f16* dst = aout + (size_t)(b * T + tok) * E + h * 64 + lr;
#pragma unroll
    for (int dt = 0; dt < 4; ++dt) dst[dt * 16] = (f16)(acc[dt][i] * inv);
  }
}

// ---------------- launch ----------------
extern "C" void kernel_launch(void* const* d_in, const int* in_sizes, int n_in,
                              void* d_out, int out_size, void* d_ws,
                              size_t ws_size, hipStream_t stream) {
  const float* x = (const float*)d_in[0];
  const float* wq = (const float*)d_in[1];
  const float* bq = (const float*)d_in[2];
  const float* wk = (const float*)d_in[3];
  const float* bk = (const float*)d_in[4];
  const float* wv = (const float*)d_in[5];
  const float* bv = (const float*)d_in[6];
  const float* wo = (const float*)d_in[7];
  const float* bo = (const float*)d_in[8];
  const float* qn_w = (const float*)d_in[9];
  const float* kn_w = (const float*)d_in[10];
  float* out = (float*)d_out;

  char* ws = (char*)d_ws;
  const size_t MB = 1u << 20;
  f16* xb = (f16*)(ws);              // 8 MB
  f16* wqT = (f16*)(ws + 8 * MB);    // 2 MB
  f16* wkT = (f16*)(ws + 10 * MB);   // 2 MB
  f16* wvT = (f16*)(ws + 12 * MB);   // 2 MB
  f16* woT = (f16*)(ws + 14 * MB);   // 2 MB
  f16* qn = (f16*)(ws + 16 * MB);    // 8 MB
  f16* kn = (f16*)(ws + 24 * MB);    // 8 MB
  f16* Vt = (f16*)(ws + 32 * MB);    // 8 MB
  f16* aout = (f16*)(ws + 40 * MB);  // 8 MB

  cast_x_kernel<<<4096, 256, 0, stream>>>(x, xb);
  transpose_w_kernel<<<dim3(16, 16, 4), 256, 0, stream>>>(wq, wk, wv, wo, wqT,
                                                          wkT, wvT, woT);
  gemm_bt_kernel<1><<<dim3(256, 1, 3), 256, 0, stream>>>(
      xb, wqT, wkT, wvT, bq, bk, bv, qn_w, kn_w, qn, kn, Vt, nullptr, 4096,
      1024, 1024);
  attn_kernel<<<1024, 256, 0, stream>>>(qn, kn, Vt, aout);
  gemm_bt_kernel<0><<<dim3(256, 1, 1), 256, 0, stream>>>(
      aout, woT, woT, woT, bo, bo, bo, nullptr, nullptr, nullptr, nullptr,
      nullptr, out, 4096, 1024, 1024);
}